// Round 12
// baseline (270.125 us; speedup 1.0000x reference)
//
#include <hip/hip_runtime.h>
#include <hip/hip_bf16.h>

#define B_ 8
#define L1_ 2048
#define L2_ 2048
#define C_ 320
#define H_ 8
#define D_ 64
#define NREG_ 4
#define INNER_ 512
#define LK_ 2052
#define LKP_ 2112   /* 33*64 padded key length */
#define NKV_TILES 33
#define LOG2E 1.44269504f
#define QSCALE (0.125f * LOG2E)   /* folded into Wq at transpose time */

// KV ORDER: [ctx (0..2047) | reg tokens (2048..2051) | pad] — mask byte idx == kv.

typedef __bf16 bf16_t;
typedef __attribute__((ext_vector_type(8))) __bf16 bf16x8;
typedef __attribute__((ext_vector_type(4))) __bf16 bf16x4;
typedef __attribute__((ext_vector_type(4))) float f32x4;
typedef __attribute__((ext_vector_type(4))) unsigned int u32x4;

__device__ __forceinline__ f32x4 mfma16(bf16x8 a, bf16x8 b, f32x4 c){
  return __builtin_amdgcn_mfma_f32_16x16x32_bf16(a, b, c, 0, 0, 0);
}

__device__ __forceinline__ void gl_lds16(const char* g, char* l){
  __builtin_amdgcn_global_load_lds(
      (const __attribute__((address_space(1))) unsigned int*)g,
      (__attribute__((address_space(3))) unsigned int*)l, 16, 0, 0);
}

__device__ __forceinline__ float fexp2(float x){
  float r; asm("v_exp_f32 %0, %1" : "=v"(r) : "v"(x)); return r;
}

__device__ __forceinline__ unsigned cvtpk(float a, float b){
  unsigned r; asm("v_cvt_pk_bf16_f32 %0, %1, %2" : "=v"(r) : "v"(a), "v"(b)); return r;
}

__device__ __forceinline__ unsigned byte2bits(unsigned u){
  unsigned b = 0;
  b |= (u & 0x000000FFu) ? 1u : 0u;
  b |= (u & 0x0000FF00u) ? 2u : 0u;
  b |= (u & 0x00FF0000u) ? 4u : 0u;
  b |= (u & 0xFF000000u) ? 8u : 0u;
  return b;
}

__device__ __forceinline__ int swzK(int row){ return (row & 3) | ((row >> 1) & 4); }
__device__ __forceinline__ int swzV(int row){ return row & 7; }

// ---------------- prep: weight transposes + fp32->bf16 cvt (2 groups/thread) ----
// blocks [0,1024): transpose; [1024,3584): x cvt; [3584,6224): ctx cvt.
__global__ __launch_bounds__(256)
void k_prep(const float* __restrict__ Wq, const float* __restrict__ Wk,
            const float* __restrict__ Wv, const float* __restrict__ Wo,
            bf16_t* __restrict__ Wqt, bf16_t* __restrict__ Wkt,
            bf16_t* __restrict__ Wvt, bf16_t* __restrict__ Wot,
            const float* __restrict__ x, const float* __restrict__ ctx,
            const float* __restrict__ regt,
            bf16_t* __restrict__ xb, bf16_t* __restrict__ ctxb)
{
  int bid = blockIdx.x;
  int tid = threadIdx.x;
  if (bid < 1024){
    int z = bid >> 8, r = bid & 255, bx = r & 15, by = r >> 4;
    int K = (z < 3) ? C_ : INNER_;
    int N = (z < 3) ? INNER_ : C_;
    if (bx * 32 >= N || by * 32 >= K) return;
    const float* W = (z == 0) ? Wq : (z == 1) ? Wk : (z == 2) ? Wv : Wo;
    bf16_t* Wt = (z == 0) ? Wqt : (z == 1) ? Wkt : (z == 2) ? Wvt : Wot;
    float sc = (z == 0) ? QSCALE : 1.0f;
    __shared__ float t[32][33];
    int n0 = bx * 32, k0 = by * 32;
    int tx = tid & 31, ty = tid >> 5;
    for (int rr = ty; rr < 32; rr += 8) t[rr][tx] = W[(long)(k0 + rr) * N + n0 + tx];
    __syncthreads();
    for (int rr = ty; rr < 32; rr += 8) Wt[(long)(n0 + rr) * K + k0 + tx] = (bf16_t)(t[tx][rr] * sc);
  } else if (bid < 3584){
    // x: two consecutive f32x4 groups per thread -> one bf16x8 store
    long g0 = ((long)(bid - 1024) * 256 + tid) * 2;
    f32x4 v0 = *(const f32x4*)(x + g0 * 4);
    f32x4 v1 = *(const f32x4*)(x + g0 * 4 + 4);
    union { u32x4 u; bf16x8 v; } pk;
    pk.u = (u32x4){cvtpk(v0[0], v0[1]), cvtpk(v0[2], v0[3]),
                   cvtpk(v1[0], v1[1]), cvtpk(v1[2], v1[3])};
    *(bf16x8*)(xb + g0 * 4) = pk.v;
  } else {
    // ctx: [ctx | reg | pad]; ctxb offset == g*4 (dense), loads need per-group row/col
    long g0 = ((long)(bid - 3584) * 256 + tid) * 2;
    f32x4 vv[2];
    #pragma unroll
    for (int gg = 0; gg < 2; gg++){
      long g = g0 + gg;
      long row = g / 80;
      int col = (int)(g - row * 80) * 4;
      int b = (int)(row / LKP_);
      int rr = (int)(row - (long)b * LKP_);
      f32x4 v = (f32x4){0,0,0,0};
      if (rr < L2_)      v = *(const f32x4*)(ctx + ((long)(b * L1_ + rr)) * C_ + col);
      else if (rr < LK_) v = *(const f32x4*)(regt + (rr - L2_) * C_ + col);
      vv[gg] = v;
    }
    union { u32x4 u; bf16x8 v; } pk;
    pk.u = (u32x4){cvtpk(vv[0][0], vv[0][1]), cvtpk(vv[0][2], vv[0][3]),
                   cvtpk(vv[1][0], vv[1][1]), cvtpk(vv[1][2], vv[1][3])};
    *(bf16x8*)(ctxb + g0 * 4) = pk.v;
  }
}

// ---------------- fused Q/K/V projection GEMMs + mask-pack tail ----------------
// GEMM: XCD-chunked 1600-block layout (as R9). Tail: grid-stride mask packing
// (memory-bound, co-scheduled under the MFMA-bound GEMM blocks; consumer is k_attn).
__global__ __launch_bounds__(256)
void k_proj(const bf16_t* __restrict__ xb, const bf16_t* __restrict__ ctxb,
            const bf16_t* __restrict__ Wqt, const bf16_t* __restrict__ Wkt,
            const bf16_t* __restrict__ Wvt,
            bf16_t* __restrict__ Qw, bf16_t* __restrict__ Kw, bf16_t* __restrict__ Vtw,
            const void* __restrict__ maskv, unsigned int* __restrict__ maskp)
{
  int lin = blockIdx.x;
  int xcd = lin & 7, idx = lin >> 3;
  int mode, mt_, n_;
  if (idx < 64){
    mode = 0;
    mt_ = xcd * 16 + (idx & 15);
    n_ = idx >> 4;
  } else {
    int j = idx - 64;
    mode = 1 + (j & 1);
    int jj = j >> 1;
    n_ = jj & 3;
    int mm = jj >> 2;
    mt_ = mm * 8 + xcd;
  }
  int tid = threadIdx.x;
  bool valid = (mode == 0) || (mt_ < 132);

  if (valid){
    const char* Ab = (const char*)((mode == 0) ? xb : ctxb);
    const char* Wtb = (const char*)((mode == 0) ? Wqt : (mode == 1) ? Wkt : Wvt);
    bf16_t* out = (mode == 0) ? Qw : (mode == 1) ? Kw : Vtw;

    __shared__ __align__(16) char As[2][128*64*2];
    __shared__ __align__(16) char Bs[2][128*64*2];
    int w = tid >> 6, lane = tid & 63, cl = lane & 15, cg = lane >> 4;
    int wr = w >> 1, wc = w & 1;
    int m0 = mt_ * 128, n0 = n_ * 128;

    f32x4 acc[4][4];
    #pragma unroll
    for (int i = 0; i < 4; i++)
      #pragma unroll
      for (int j = 0; j < 4; j++) acc[i][j] = (f32x4){0,0,0,0};

    auto stage = [&](int kb, int buf){
      #pragma unroll
      for (int c = 0; c < 4; c++){
        int e = c * 4096 + tid * 16;
        int row = e >> 7, irb = e & 127;
        gl_lds16(Ab + (long)(m0 + row) * 640 + kb * 128 + (irb ^ ((row & 7) << 4)), As[buf] + e);
      }
      #pragma unroll
      for (int c = 0; c < 4; c++){
        int e = c * 4096 + tid * 16;
        int row = e >> 7, irb = e & 127;
        gl_lds16(Wtb + (long)(n0 + row) * 640 + kb * 128 + (irb ^ ((row & 7) << 4)), Bs[buf] + e);
      }
    };

    stage(0, 0);
    for (int kb = 0; kb < 5; ++kb){
      int buf = kb & 1;
      if (kb < 4){
        stage(kb + 1, buf ^ 1);
        asm volatile("s_waitcnt vmcnt(8)" ::: "memory");
      } else {
        asm volatile("s_waitcnt vmcnt(0)" ::: "memory");
      }
      __syncthreads();
      #pragma unroll
      for (int kc = 0; kc < 2; kc++){
        int kk = kc * 32 + cg * 8;
        bf16x8 af[4], bfr[4];
        #pragma unroll
        for (int mt = 0; mt < 4; mt++){
          int row = wr * 64 + mt * 16 + cl;
          af[mt] = *(const bf16x8*)(As[buf] + (row << 7) + ((kk << 1) ^ ((row & 7) << 4)));
        }
        #pragma unroll
        for (int nt = 0; nt < 4; nt++){
          int row = wc * 64 + nt * 16 + cl;
          bfr[nt] = *(const bf16x8*)(Bs[buf] + (row << 7) + ((kk << 1) ^ ((row & 7) << 4)));
        }
        #pragma unroll
        for (int mt = 0; mt < 4; mt++)
          #pragma unroll
          for (int nt = 0; nt < 4; nt++)
            acc[mt][nt] = mfma16(af[mt], bfr[nt], acc[mt][nt]);
      }
      __syncthreads();
    }

    #pragma unroll
    for (int mt = 0; mt < 4; mt++){
      #pragma unroll
      for (int nt = 0; nt < 4; nt++){
        f32x4 v = acc[mt][nt];
        int row = m0 + wr * 64 + mt * 16 + cg * 4;
        int col = n0 + wc * 64 + nt * 16 + cl;
        int h = col >> 6, d = col & 63;
        if (mode == 0){
          int b = row >> 11, l1 = row & 2047;
          bf16_t* p = out + ((long)((b * H_ + h) * L1_ + l1)) * D_ + d;
          #pragma unroll
          for (int r = 0; r < 4; r++) p[r * D_] = (bf16_t)v[r];
        } else if (mode == 1){
          int b = row / LKP_, rr = row - b * LKP_;
          bf16_t* p = out + ((long)((b * H_ + h) * LKP_ + rr)) * D_ + d;
          #pragma unroll
          for (int r = 0; r < 4; r++) p[r * D_] = (bf16_t)v[r];
        } else {
          int b = row / LKP_, rr = row - b * LKP_;
          bf16x4 cv;
          cv[0]=(bf16_t)v[0]; cv[1]=(bf16_t)v[1]; cv[2]=(bf16_t)v[2]; cv[3]=(bf16_t)v[3];
          *(bf16x4*)(out + ((long)((b * H_ + h) * D_ + d)) * LKP_ + rr) = cv;
        }
      }
    }
  }

  // ---- mask-pack tail: grid-stride over 4096 row-quads ----
  {
    int l = tid & 63;
    const unsigned char* mb = (const unsigned char*)maskv;
    const int* mi = (const int*)maskv;
    int bad = 0;
    #pragma unroll
    for (int jj = 0; jj < 4; jj++){
      int j = l + jj * 64;
      if ((j & 3) != 0 && mb[j] != 0) bad = 1;
    }
    int isInt = (__ballot(bad) == 0ull) ? 1 : 0;
    for (int mq = lin; mq < 4096; mq += 1600){
      int row = mq * 4 + (tid >> 6);
      unsigned int* orow = maskp + (long)row * 66;
      if (!isInt){
        const unsigned char* rp = mb + (long)row * L2_;
        u32x4 a = *(const u32x4*)(rp + 32 * l);
        u32x4 c = *(const u32x4*)(rp + 32 * l + 16);
        unsigned wdv = 0;
        wdv |= byte2bits(a[0]);
        wdv |= byte2bits(a[1]) << 4;
        wdv |= byte2bits(a[2]) << 8;
        wdv |= byte2bits(a[3]) << 12;
        wdv |= byte2bits(c[0]) << 16;
        wdv |= byte2bits(c[1]) << 20;
        wdv |= byte2bits(c[2]) << 24;
        wdv |= byte2bits(c[3]) << 28;
        orow[l] = wdv;
        if (l == 0) orow[64] = 0x0000000Fu;
        else if (l == 1) orow[65] = 0u;
      } else {
        long base = (long)row * L2_;
        for (int s = 0; s < 33; s++){
          int kv = s * 64 + l;
          int vis;
          if (kv < L2_) vis = (mi[base + kv] != 0);
          else          vis = (kv < LK_);
          unsigned long long bal = __ballot(vis);
          if (l == 0)      orow[2*s]   = (unsigned int)bal;
          else if (l == 1) orow[2*s+1] = (unsigned int)(bal >> 32);
        }
      }
    }
  }
}

// ---------------- flash attention (frozen from R9) ----------------
__global__ __launch_bounds__(512)
void k_attn(const bf16_t* __restrict__ Q, const bf16_t* __restrict__ K,
            const bf16_t* __restrict__ Vt, const unsigned int* __restrict__ maskp,
            bf16_t* __restrict__ att)
{
  __shared__ __align__(16) char smem[33024]; // K:2x8KB @0, V:2x8KB @16384, LUT @32768
  int lin = blockIdx.x;
  int xcd = lin & 7, idx = lin >> 3;
  int bh = xcd * 8 + (idx >> 3);
  int qb = idx & 7;
  const int b = bh >> 3, h = bh & 7;
  const int tid = threadIdx.x, w = tid >> 6, lane = tid & 63;
  const int cl = lane & 15, cg = lane >> 4;
  const int qw = qb * 256 + w * 32;

  char* lutb = smem + 32768;
  if (tid < 16){
    unsigned n = tid;
    uint2 mk;
    mk.x = ((n & 1u) ? 0x0000FFFFu : 0u) | ((n & 2u) ? 0xFFFF0000u : 0u);
    mk.y = ((n & 4u) ? 0x0000FFFFu : 0u) | ((n & 8u) ? 0xFFFF0000u : 0u);
    *(uint2*)(lutb + tid * 8) = mk;
  }

  const char* Kg = (const char*)(K + (long)bh * LKP_ * D_);
  const char* Vg = (const char*)(Vt + (long)bh * D_ * LKP_);

  bf16x8 qf[2][2];
  const unsigned int* mrow[2];
  #pragma unroll
  for (int qg = 0; qg < 2; qg++){
    const bf16_t* Qb = Q + ((long)bh * L1_ + qw + qg*16 + cl) * D_;
    qf[qg][0] = *(const bf16x8*)(Qb + cg*8);
    qf[qg][1] = *(const bf16x8*)(Qb + 32 + cg*8);
    mrow[qg] = maskp + (long)(b * L1_ + qw + qg*16 + cl) * 66;
  }

  bf16x8 ones8;
  #pragma unroll
  for (int i = 0; i < 8; i++) ones8[i] = (bf16_t)1.0f;

  f32x4 o[2][4];
  f32x4 sacc[2];
  #pragma unroll
  for (int qg = 0; qg < 2; qg++){
    sacc[qg] = (f32x4){0,0,0,0};
    #pragma unroll
    for (int dt = 0; dt < 4; dt++) o[qg][dt] = (f32x4){0,0,0,0};
  }

  const int sp = tid * 16;
  const int srow = sp >> 7, sir = sp & 127;
  const int kgo = (srow << 7) + (sir ^ (swzK(srow) << 4));
  const long vgo = (long)srow * (LKP_ * 2) + (sir ^ (swzV(srow) << 4));

  gl_lds16(Kg + kgo, smem + sp);
  gl_lds16(Vg + vgo, smem + 16384 + sp);
  uint2 wd_cur[2];
  #pragma unroll
  for (int qg = 0; qg < 2; qg++) wd_cur[qg] = *(const uint2*)(mrow[qg]);
  asm volatile("s_waitcnt vmcnt(0)" ::: "memory");
  __syncthreads();

  for (int t = 0; t < NKV_TILES; ++t){
    int tn = (t + 1 < NKV_TILES) ? t + 1 : NKV_TILES - 1;
    gl_lds16(Kg + (long)tn * 8192 + kgo, smem + ((t + 1) & 1) * 8192 + sp);
    gl_lds16(Vg + vgo + tn * 128, smem + 16384 + ((t + 1) & 1) * 8192 + sp);
    uint2 wd_nxt[2];
    #pragma unroll
    for (int qg = 0; qg < 2; qg++) wd_nxt[qg] = *(const uint2*)(mrow[qg] + 2*tn);

    const char* Kb = smem + (t & 1) * 8192;
    const char* Vb = smem + 16384 + (t & 1) * 8192;

    f32x4 s[2][4];
    __builtin_amdgcn_s_setprio(1);
    #pragma unroll
    for (int T = 0; T < 4; T++){
      int row = 32*(T>>1) + 8*(cl>>2) + 4*(T&1) + (cl&3);
      int sw = swzK(row) << 4;
      const char* rp = Kb + (row << 7);
      bf16x8 kf0 = *(const bf16x8*)(rp + ((16*cg) ^ sw));
      bf16x8 kf1 = *(const bf16x8*)(rp + ((64 + 16*cg) ^ sw));
      #pragma unroll
      for (int qg = 0; qg < 2; qg++){
        f32x4 z = (f32x4){0,0,0,0};
        z = mfma16(kf0, qf[qg][0], z);
        z = mfma16(kf1, qf[qg][1], z);
        s[qg][T] = z;
      }
    }
    __builtin_amdgcn_s_setprio(0);

    bf16x8 pa[2][2];
    #pragma unroll
    for (int qg = 0; qg < 2; qg++){
      unsigned wrd[2][4];
      #pragma unroll
      for (int T = 0; T < 4; T++){
        unsigned wsel = (T < 2) ? wd_cur[qg].x : wd_cur[qg].y;
        unsigned nib = (wsel >> (8*cg + 4*(T&1))) & 0xFu;
        uint2 mk = *(const uint2*)(lutb + (nib << 3));
        float p0 = fexp2(s[qg][T][0]);
        float p1 = fexp2(s[qg][T][1]);
        float p2 = fexp2(s[qg][T][2]);
        float p3 = fexp2(s[qg][T][3]);
        unsigned lo = cvtpk(p0, p1) & mk.x;
        unsigned hi = cvtpk(p2, p3) & mk.y;
        wrd[T >> 1][2*(T & 1) + 0] = lo;
        wrd[T >> 1][2*(T & 1) + 1] = hi;
      }
      union { u32x4 u; bf16x8 v; } pk0, pk1;
      pk0.u = (u32x4){wrd[0][0], wrd[0][1], wrd[0][2], wrd[0][3]};
      pk1.u = (u32x4){wrd[1][0], wrd[1][1], wrd[1][2], wrd[1][3]};
      pa[qg][0] = pk0.v;
      pa[qg][1] = pk1.v;
    }

    __builtin_amdgcn_s_setprio(1);
    #pragma unroll
    for (int qg = 0; qg < 2; qg++){
      sacc[qg] = mfma16(ones8, pa[qg][0], sacc[qg]);
      sacc[qg] = mfma16(ones8, pa[qg][1], sacc[qg]);
    }
    #pragma unroll
    for (int dt = 0; dt < 4; dt++){
      int row = 16*dt + cl;
      int sw = swzV(row) << 4;
      const char* rp = Vb + (row << 7);
      bf16x8 vf0 = *(const bf16x8*)(rp + ((16*cg) ^ sw));
      bf16x8 vf1 = *(const bf16x8*)(rp + ((64 + 16*cg) ^ sw));
      #pragma unroll
      for (int qg = 0; qg < 2; qg++){
        o[qg][dt] = mfma16(pa[qg][0], vf0, o[qg][dt]);
        o[qg][dt] = mfma16(pa[qg][1], vf1, o[qg][dt]);
      }
    }
    __builtin_amdgcn_s_setprio(0);

    asm volatile("s_waitcnt vmcnt(0)" ::: "memory");
    __syncthreads();
    wd_cur[0] = wd_nxt[0];
    wd_cur[1] = wd_nxt[1];
  }

  #pragma unroll
  for (int qg = 0; qg < 2; qg++){
    float inv = 1.0f / sacc[qg][0];
    float ir0 = __shfl(inv, (lane & 48) | (cg*4 + 0));
    float ir1 = __shfl(inv, (lane & 48) | (cg*4 + 1));
    float ir2 = __shfl(inv, (lane & 48) | (cg*4 + 2));
    float ir3 = __shfl(inv, (lane & 48) | (cg*4 + 3));
    int qbase = qw + qg*16 + cg*4;
    #pragma unroll
    for (int dt = 0; dt < 4; dt++){
      bf16_t* op = att + ((long)(b * L1_) + qbase) * INNER_ + h * D_ + 16*dt + cl;
      op[0] = (bf16_t)(o[qg][dt][0] * ir0);
      op[INNER_] = (bf16_t)(o[qg][dt][1] * ir1);
      op[2*INNER_] = (bf16_t)(o[qg][dt][2] * ir2);
      op[3*INNER_] = (bf16_t)(o[qg][dt][3] * ir3);
    }
  }
}

// ---------------- output GEMM, XCD-chunked 1D grid ----------------
__global__ __launch_bounds__(256)
void k_out(const bf16_t* __restrict__ A, const bf16_t* __restrict__ Wot,
           const float* __restrict__ bo, float* __restrict__ out)
{
  __shared__ __align__(16) char As[2][128*64*2];
  __shared__ __align__(16) char Bs[2][64*64*2];
  int lin = blockIdx.x;
  int xcd = lin & 7, idx = lin >> 3;
  int tid = threadIdx.x;
  int w = tid >> 6, lane = tid & 63, cl = lane & 15, cg = lane >> 4;
  int wr = w >> 1, wc = w & 1;
  int m0 = (xcd * 16 + (idx & 15)) * 128, n0 = (idx >> 4) * 64;
  const char* Ab = (const char*)A;
  const char* Bb = (const char*)Wot;

  f32x4 acc[4][2];
  #pragma unroll
  for (int i = 0; i < 4; i++)
    #pragma unroll
    for (int j = 0; j < 2; j++) acc[i][j] = (f32x4){0,0,0,0};

  auto stage = [&](int kb, int buf){
    #pragma unroll
    for (int c = 0; c < 4; c++){
      int e = c * 4096 + tid * 16;
      int row = e >> 7, irb = e & 127;
      gl_lds16(Ab + (long)(m0 + row) * 1024 + kb * 128 + (irb ^ ((row & 7) << 4)), As[buf] + e);
    }
    #pragma unroll
    for (int c = 0; c < 2; c++){
      int e = c * 4096 + tid * 16;
      int row = e >> 7, irb = e & 127;
      gl_lds16(Bb + (long)(n0 + row) * 1024 + kb * 128 + (irb ^ ((row & 7) << 4)), Bs[buf] + e);
    }
  };

  stage(0, 0);
  for (int kb = 0; kb < 8; kb++){
    int buf = kb & 1;
    if (kb < 7){
      stage(kb + 1, buf ^ 1);
      asm volatile("s_waitcnt vmcnt(6)" ::: "memory");
    } else {
      asm volatile("s_waitcnt vmcnt(0)" ::: "memory");
    }
    __syncthreads();
    #pragma unroll
    for (int kc = 0; kc < 2; kc++){
      int kk = kc * 32 + cg * 8;
      bf16x8 af[4], bfr[2];
      #pragma unroll
      for (int mt = 0; mt < 4; mt++){
        int row = wr * 64 + mt * 16 + cl;
        af[mt] = *(const bf16x8*)(As[buf] + (row << 7) + ((kk << 1) ^ ((row & 7) << 4)));
      }
      #pragma unroll
      for (int nt = 0; nt < 2; nt++){
        int row = wc * 32 + nt * 16 + cl;
        bfr[nt] = *(const bf16x8*)(Bs[buf] + (row << 7) + ((kk << 1) ^ ((row & 7) << 4)));
      }
      #pragma unroll
      for (int mt = 0; mt < 4; mt++)
        #pragma unroll
        for (int nt = 0; nt < 2; nt++)
          acc[mt][nt] = mfma16(af[mt], bfr[nt], acc[mt][nt]);
    }
    __syncthreads();
  }
  #pragma unroll
  for (int mt = 0; mt < 4; mt++)
    #pragma unroll
    for (int nt = 0; nt < 2; nt++){
      int row = m0 + wr * 64 + mt * 16 + cg * 4;
      int col = n0 + wc * 32 + nt * 16 + cl;
      float bias = bo[col];
      #pragma unroll
      for (int r = 0; r < 4; r++)
        out[(long)(row + r) * C_ + col] = acc[mt][nt][r] + bias;
    }
}

extern "C" void kernel_launch(void* const* d_in, const int* in_sizes, int n_in,
                              void* d_out, int out_size, void* d_ws, size_t ws_size,
                              hipStream_t stream)
{
  const float* x    = (const float*)d_in[0];
  const float* ctx  = (const float*)d_in[1];
  const void*  mask = d_in[2];
  const float* Wq   = (const float*)d_in[3];
  const float* Wk   = (const float*)d_in[4];
  const float* Wv   = (const float*)d_in[5];
  const float* Wo   = (const float*)d_in[6];
  const float* bo   = (const float*)d_in[7];
  const float* regt = (const float*)d_in[8];
  float* out = (float*)d_out;

  char* ws = (char*)d_ws;
  size_t off = 256;
  unsigned int* maskp = (unsigned int*)(ws + off);    off += (size_t)16384 * 66 * 4;
  bf16_t* Qw  = (bf16_t*)(ws + off);                  off += (size_t)B_*H_*L1_*D_*2;
  bf16_t* Kw  = (bf16_t*)(ws + off);                  off += (size_t)B_*H_*LKP_*D_*2;
  bf16_t* Vtw = (bf16_t*)(ws + off);                  off += (size_t)B_*H_*D_*LKP_*2;
  size_t Roff = off;
  bf16_t* xb   = (bf16_t*)(ws + Roff);
  bf16_t* ctxb = (bf16_t*)(ws + Roff + (size_t)16384*C_*2);
  bf16_t* Att  = (bf16_t*)(ws + Roff);
  off = Roff + (size_t)16384*C_*2 + (size_t)16896*C_*2;
  bf16_t* Wqt = (bf16_t*)(ws + off);                  off += (size_t)C_*INNER_*2;
  bf16_t* Wkt = (bf16_t*)(ws + off);                  off += (size_t)C_*INNER_*2;
  bf16_t* Wvt = (bf16_t*)(ws + off);                  off += (size_t)C_*INNER_*2;
  bf16_t* Wot = (bf16_t*)(ws + off);                  off += (size_t)C_*INNER_*2;
  (void)ws_size; (void)in_sizes; (void)n_in; (void)out_size;

  k_prep<<<6224, 256, 0, stream>>>(Wq, Wk, Wv, Wo, Wqt, Wkt, Wvt, Wot,
                                   x, ctx, regt, xb, ctxb);
  k_proj<<<1600, 256, 0, stream>>>(xb, ctxb, Wqt, Wkt, Wvt, Qw, Kw, Vtw, mask, maskp);
  k_attn<<<512, 512, 0, stream>>>(Qw, Kw, Vtw, maskp, Att);
  k_out<<<640, 256, 0, stream>>>(Att, Wot, bo, out);
}

// Round 13
// 223.286 us; speedup vs baseline: 1.2098x; 1.2098x over previous
//
#include <hip/hip_runtime.h>
#include <hip/hip_bf16.h>

#define B_ 8
#define L1_ 2048
#define L2_ 2048
#define C_ 320
#define H_ 8
#define D_ 64
#define NREG_ 4
#define INNER_ 512
#define LK_ 2052
#define LKP_ 2112   /* 33*64 padded key length */
#define NKV_TILES 33
#define LOG2E 1.44269504f
#define QSCALE (0.125f * LOG2E)   /* folded into Wq at transpose time */

// KV ORDER: [ctx (0..2047) | reg tokens (2048..2051) | pad] — mask byte idx == kv.

typedef __bf16 bf16_t;
typedef __attribute__((ext_vector_type(8))) __bf16 bf16x8;
typedef __attribute__((ext_vector_type(4))) __bf16 bf16x4;
typedef __attribute__((ext_vector_type(4))) float f32x4;
typedef __attribute__((ext_vector_type(4))) unsigned int u32x4;

__device__ __forceinline__ f32x4 mfma16(bf16x8 a, bf16x8 b, f32x4 c){
  return __builtin_amdgcn_mfma_f32_16x16x32_bf16(a, b, c, 0, 0, 0);
}

__device__ __forceinline__ void gl_lds16(const char* g, char* l){
  __builtin_amdgcn_global_load_lds(
      (const __attribute__((address_space(1))) unsigned int*)g,
      (__attribute__((address_space(3))) unsigned int*)l, 16, 0, 0);
}

__device__ __forceinline__ float fexp2(float x){
  float r; asm("v_exp_f32 %0, %1" : "=v"(r) : "v"(x)); return r;
}

__device__ __forceinline__ unsigned cvtpk(float a, float b){
  unsigned r; asm("v_cvt_pk_bf16_f32 %0, %1, %2" : "=v"(r) : "v"(a), "v"(b)); return r;
}

__device__ __forceinline__ unsigned byte2bits(unsigned u){
  unsigned b = 0;
  b |= (u & 0x000000FFu) ? 1u : 0u;
  b |= (u & 0x0000FF00u) ? 2u : 0u;
  b |= (u & 0x00FF0000u) ? 4u : 0u;
  b |= (u & 0xFF000000u) ? 8u : 0u;
  return b;
}

__device__ __forceinline__ int swzK(int row){ return (row & 3) | ((row >> 1) & 4); }
__device__ __forceinline__ int swzV(int row){ return row & 7; }

// ---------------- prep: weight transposes + mask pack (NO cvt pass) ----------------
// blocks [0,1024): transpose; [1024,5120): mask row-quads.
__global__ __launch_bounds__(256)
void k_prep(const float* __restrict__ Wq, const float* __restrict__ Wk,
            const float* __restrict__ Wv, const float* __restrict__ Wo,
            bf16_t* __restrict__ Wqt, bf16_t* __restrict__ Wkt,
            bf16_t* __restrict__ Wvt, bf16_t* __restrict__ Wot,
            const void* __restrict__ maskv, unsigned int* __restrict__ maskp)
{
  int bid = blockIdx.x;
  int tid = threadIdx.x;
  if (bid < 1024){
    int z = bid >> 8, r = bid & 255, bx = r & 15, by = r >> 4;
    int K = (z < 3) ? C_ : INNER_;
    int N = (z < 3) ? INNER_ : C_;
    if (bx * 32 >= N || by * 32 >= K) return;
    const float* W = (z == 0) ? Wq : (z == 1) ? Wk : (z == 2) ? Wv : Wo;
    bf16_t* Wt = (z == 0) ? Wqt : (z == 1) ? Wkt : (z == 2) ? Wvt : Wot;
    float sc = (z == 0) ? QSCALE : 1.0f;
    __shared__ float t[32][33];
    int n0 = bx * 32, k0 = by * 32;
    int tx = tid & 31, ty = tid >> 5;
    for (int rr = ty; rr < 32; rr += 8) t[rr][tx] = W[(long)(k0 + rr) * N + n0 + tx];
    __syncthreads();
    for (int rr = ty; rr < 32; rr += 8) Wt[(long)(n0 + rr) * K + k0 + tx] = (bf16_t)(t[tx][rr] * sc);
  } else {
    int row = (bid - 1024) * 4 + (tid >> 6);
    int l = tid & 63;
    const unsigned char* mb = (const unsigned char*)maskv;
    const int* mi = (const int*)maskv;
    int bad = 0;
    #pragma unroll
    for (int jj = 0; jj < 4; jj++){
      int j = l + jj * 64;
      if ((j & 3) != 0 && mb[j] != 0) bad = 1;
    }
    int isInt = (__ballot(bad) == 0ull) ? 1 : 0;
    unsigned int* orow = maskp + (long)row * 66;
    if (!isInt){
      const unsigned char* rp = mb + (long)row * L2_;
      u32x4 a = *(const u32x4*)(rp + 32 * l);
      u32x4 c = *(const u32x4*)(rp + 32 * l + 16);
      unsigned wdv = 0;
      wdv |= byte2bits(a[0]);
      wdv |= byte2bits(a[1]) << 4;
      wdv |= byte2bits(a[2]) << 8;
      wdv |= byte2bits(a[3]) << 12;
      wdv |= byte2bits(c[0]) << 16;
      wdv |= byte2bits(c[1]) << 20;
      wdv |= byte2bits(c[2]) << 24;
      wdv |= byte2bits(c[3]) << 28;
      orow[l] = wdv;
      if (l == 0) orow[64] = 0x0000000Fu;
      else if (l == 1) orow[65] = 0u;
    } else {
      long base = (long)row * L2_;
      for (int s = 0; s < 33; s++){
        int kv = s * 64 + l;
        int vis;
        if (kv < L2_) vis = (mi[base + kv] != 0);
        else          vis = (kv < LK_);
        unsigned long long bal = __ballot(vis);
        if (l == 0)      orow[2*s]   = (unsigned int)bal;
        else if (l == 1) orow[2*s+1] = (unsigned int)(bal >> 32);
      }
    }
  }
}

// ---------------- fused Q/K/V projection GEMMs, fp32-A reg-staging ----------------
// A read directly in fp32 (no cvt pass): f32x4 loads -> cvt_pk -> swizzled ds_write.
// B (bf16 weights) via global_load_lds. Single-buffered 32KB LDS, 2-barrier loop.
// XCD-chunked 1600-block 1D grid (R9 mapping).
__global__ __launch_bounds__(256)
void k_proj(const float* __restrict__ x, const float* __restrict__ ctx,
            const float* __restrict__ regt,
            const bf16_t* __restrict__ Wqt, const bf16_t* __restrict__ Wkt,
            const bf16_t* __restrict__ Wvt,
            bf16_t* __restrict__ Qw, bf16_t* __restrict__ Kw, bf16_t* __restrict__ Vtw)
{
  int lin = blockIdx.x;
  int xcd = lin & 7, idx = lin >> 3;
  int mode, mt_, n_;
  if (idx < 64){
    mode = 0;
    mt_ = xcd * 16 + (idx & 15);
    n_ = idx >> 4;
  } else {
    int j = idx - 64;
    mode = 1 + (j & 1);
    int jj = j >> 1;
    n_ = jj & 3;
    int mm = jj >> 2;
    mt_ = mm * 8 + xcd;
    if (mt_ >= 132) return;
  }
  const bf16_t* Wt = (mode == 0) ? Wqt : (mode == 1) ? Wkt : Wvt;
  const char* Wtb = (const char*)Wt;
  bf16_t* out = (mode == 0) ? Qw : (mode == 1) ? Kw : Vtw;

  __shared__ __align__(16) char As[128*64*2];
  __shared__ __align__(16) char Bs[128*64*2];
  int tid = threadIdx.x;
  int w = tid >> 6, lane = tid & 63, cl = lane & 15, cg = lane >> 4;
  int wr = w >> 1, wc = w & 1;
  int m0 = mt_ * 128, n0 = n_ * 128;

  // hoist per-row fp32 A source pointers ([ctx | reg | pad] order for kv modes)
  const float* srcs[8];
  #pragma unroll
  for (int c = 0; c < 8; c++){
    int e = c * 1024 + tid * 4;
    int row = e >> 6, k = e & 63;
    if (mode == 0){
      srcs[c] = x + (long)(m0 + row) * C_ + k;
    } else {
      int rg = m0 + row;
      int b = rg / LKP_;
      int rr = rg - b * LKP_;
      const float* src = nullptr;
      if (rr < L2_)      src = ctx + (long)(b * L1_ + rr) * C_ + k;
      else if (rr < LK_) src = regt + (long)(rr - L2_) * C_ + k;
      srcs[c] = src;
    }
  }

  f32x4 acc[4][4];
  #pragma unroll
  for (int i = 0; i < 4; i++)
    #pragma unroll
    for (int j = 0; j < 4; j++) acc[i][j] = (f32x4){0,0,0,0};

  for (int kb = 0; kb < 5; ++kb){
    int k0 = kb * 64;
    __syncthreads();
    // B staging via gl_lds (4 x 16B/thread)
    #pragma unroll
    for (int c = 0; c < 4; c++){
      int e = c * 4096 + tid * 16;
      int row = e >> 7, irb = e & 127;
      gl_lds16(Wtb + (long)(n0 + row) * 640 + kb * 128 + (irb ^ ((row & 7) << 4)), Bs + e);
    }
    // A staging: fp32 load -> cvt_pk -> swizzled 8B ds_write
    #pragma unroll
    for (int c = 0; c < 8; c++){
      int e = c * 1024 + tid * 4;
      int row = e >> 6, k = e & 63;
      f32x4 v = (f32x4){0,0,0,0};
      if (srcs[c]) v = *(const f32x4*)(srcs[c] + k0);
      uint2 pk;
      pk.x = cvtpk(v[0], v[1]);
      pk.y = cvtpk(v[2], v[3]);
      int off = (row << 7) + ((k << 1) ^ ((row & 7) << 4));
      *(uint2*)(As + off) = pk;
    }
    asm volatile("s_waitcnt vmcnt(0)" ::: "memory");
    __syncthreads();
    #pragma unroll
    for (int kc = 0; kc < 2; kc++){
      int kk = kc * 32 + cg * 8;
      bf16x8 af[4], bfr[4];
      #pragma unroll
      for (int mt = 0; mt < 4; mt++){
        int row = wr * 64 + mt * 16 + cl;
        af[mt] = *(const bf16x8*)(As + (row << 7) + ((kk << 1) ^ ((row & 7) << 4)));
      }
      #pragma unroll
      for (int nt = 0; nt < 4; nt++){
        int row = wc * 64 + nt * 16 + cl;
        bfr[nt] = *(const bf16x8*)(Bs + (row << 7) + ((kk << 1) ^ ((row & 7) << 4)));
      }
      #pragma unroll
      for (int mt = 0; mt < 4; mt++)
        #pragma unroll
        for (int nt = 0; nt < 4; nt++)
          acc[mt][nt] = mfma16(af[mt], bfr[nt], acc[mt][nt]);
    }
  }

  #pragma unroll
  for (int mt = 0; mt < 4; mt++){
    #pragma unroll
    for (int nt = 0; nt < 4; nt++){
      f32x4 v = acc[mt][nt];
      int row = m0 + wr * 64 + mt * 16 + cg * 4;
      int col = n0 + wc * 64 + nt * 16 + cl;
      int h = col >> 6, d = col & 63;
      if (mode == 0){
        int b = row >> 11, l1 = row & 2047;
        bf16_t* p = out + ((long)((b * H_ + h) * L1_ + l1)) * D_ + d;
        #pragma unroll
        for (int r = 0; r < 4; r++) p[r * D_] = (bf16_t)v[r];
      } else if (mode == 1){
        int b = row / LKP_, rr = row - b * LKP_;
        bf16_t* p = out + ((long)((b * H_ + h) * LKP_ + rr)) * D_ + d;
        #pragma unroll
        for (int r = 0; r < 4; r++) p[r * D_] = (bf16_t)v[r];
      } else {
        int b = row / LKP_, rr = row - b * LKP_;
        bf16x4 cv;
        cv[0]=(bf16_t)v[0]; cv[1]=(bf16_t)v[1]; cv[2]=(bf16_t)v[2]; cv[3]=(bf16_t)v[3];
        *(bf16x4*)(out + ((long)((b * H_ + h) * D_ + d)) * LKP_ + rr) = cv;
      }
    }
  }
}

// ---------------- flash attention (frozen from R9) ----------------
__global__ __launch_bounds__(512)
void k_attn(const bf16_t* __restrict__ Q, const bf16_t* __restrict__ K,
            const bf16_t* __restrict__ Vt, const unsigned int* __restrict__ maskp,
            bf16_t* __restrict__ att)
{
  __shared__ __align__(16) char smem[33024]; // K:2x8KB @0, V:2x8KB @16384, LUT @32768
  int lin = blockIdx.x;
  int xcd = lin & 7, idx = lin >> 3;
  int bh = xcd * 8 + (idx >> 3);
  int qb = idx & 7;
  const int b = bh >> 3, h = bh & 7;
  const int tid = threadIdx.x, w = tid >> 6, lane = tid & 63;
  const int cl = lane & 15, cg = lane >> 4;
  const int qw = qb * 256 + w * 32;

  char* lutb = smem + 32768;
  if (tid < 16){
    unsigned n = tid;
    uint2 mk;
    mk.x = ((n & 1u) ? 0x0000FFFFu : 0u) | ((n & 2u) ? 0xFFFF0000u : 0u);
    mk.y = ((n & 4u) ? 0x0000FFFFu : 0u) | ((n & 8u) ? 0xFFFF0000u : 0u);
    *(uint2*)(lutb + tid * 8) = mk;
  }

  const char* Kg = (const char*)(K + (long)bh * LKP_ * D_);
  const char* Vg = (const char*)(Vt + (long)bh * D_ * LKP_);

  bf16x8 qf[2][2];
  const unsigned int* mrow[2];
  #pragma unroll
  for (int qg = 0; qg < 2; qg++){
    const bf16_t* Qb = Q + ((long)bh * L1_ + qw + qg*16 + cl) * D_;
    qf[qg][0] = *(const bf16x8*)(Qb + cg*8);
    qf[qg][1] = *(const bf16x8*)(Qb + 32 + cg*8);
    mrow[qg] = maskp + (long)(b * L1_ + qw + qg*16 + cl) * 66;
  }

  bf16x8 ones8;
  #pragma unroll
  for (int i = 0; i < 8; i++) ones8[i] = (bf16_t)1.0f;

  f32x4 o[2][4];
  f32x4 sacc[2];
  #pragma unroll
  for (int qg = 0; qg < 2; qg++){
    sacc[qg] = (f32x4){0,0,0,0};
    #pragma unroll
    for (int dt = 0; dt < 4; dt++) o[qg][dt] = (f32x4){0,0,0,0};
  }

  const int sp = tid * 16;
  const int srow = sp >> 7, sir = sp & 127;
  const int kgo = (srow << 7) + (sir ^ (swzK(srow) << 4));
  const long vgo = (long)srow * (LKP_ * 2) + (sir ^ (swzV(srow) << 4));

  gl_lds16(Kg + kgo, smem + sp);
  gl_lds16(Vg + vgo, smem + 16384 + sp);
  uint2 wd_cur[2];
  #pragma unroll
  for (int qg = 0; qg < 2; qg++) wd_cur[qg] = *(const uint2*)(mrow[qg]);
  asm volatile("s_waitcnt vmcnt(0)" ::: "memory");
  __syncthreads();

  for (int t = 0; t < NKV_TILES; ++t){
    int tn = (t + 1 < NKV_TILES) ? t + 1 : NKV_TILES - 1;
    gl_lds16(Kg + (long)tn * 8192 + kgo, smem + ((t + 1) & 1) * 8192 + sp);
    gl_lds16(Vg + vgo + tn * 128, smem + 16384 + ((t + 1) & 1) * 8192 + sp);
    uint2 wd_nxt[2];
    #pragma unroll
    for (int qg = 0; qg < 2; qg++) wd_nxt[qg] = *(const uint2*)(mrow[qg] + 2*tn);

    const char* Kb = smem + (t & 1) * 8192;
    const char* Vb = smem + 16384 + (t & 1) * 8192;

    f32x4 s[2][4];
    __builtin_amdgcn_s_setprio(1);
    #pragma unroll
    for (int T = 0; T < 4; T++){
      int row = 32*(T>>1) + 8*(cl>>2) + 4*(T&1) + (cl&3);
      int sw = swzK(row) << 4;
      const char* rp = Kb + (row << 7);
      bf16x8 kf0 = *(const bf16x8*)(rp + ((16*cg) ^ sw));
      bf16x8 kf1 = *(const bf16x8*)(rp + ((64 + 16*cg) ^ sw));
      #pragma unroll
      for (int qg = 0; qg < 2; qg++){
        f32x4 z = (f32x4){0,0,0,0};
        z = mfma16(kf0, qf[qg][0], z);
        z = mfma16(kf1, qf[qg][1], z);
        s[qg][T] = z;
      }
    }
    __builtin_amdgcn_s_setprio(0);

    bf16x8 pa[2][2];
    #pragma unroll
    for (int qg = 0; qg < 2; qg++){
      unsigned wrd[2][4];
      #pragma unroll
      for (int T = 0; T < 4; T++){
        unsigned wsel = (T < 2) ? wd_cur[qg].x : wd_cur[qg].y;
        unsigned nib = (wsel >> (8*cg + 4*(T&1))) & 0xFu;
        uint2 mk = *(const uint2*)(lutb + (nib << 3));
        float p0 = fexp2(s[qg][T][0]);
        float p1 = fexp2(s[qg][T][1]);
        float p2 = fexp2(s[qg][T][2]);
        float p3 = fexp2(s[qg][T][3]);
        unsigned lo = cvtpk(p0, p1) & mk.x;
        unsigned hi = cvtpk(p2, p3) & mk.y;
        wrd[T >> 1][2*(T & 1) + 0] = lo;
        wrd[T >> 1][2*(T & 1) + 1] = hi;
      }
      union { u32x4 u; bf16x8 v; } pk0, pk1;
      pk0.u = (u32x4){wrd[0][0], wrd[0][1], wrd[0][2], wrd[0][3]};
      pk1.u = (u32x4){wrd[1][0], wrd[1][1], wrd[1][2], wrd[1][3]};
      pa[qg][0] = pk0.v;
      pa[qg][1] = pk1.v;
    }

    __builtin_amdgcn_s_setprio(1);
    #pragma unroll
    for (int qg = 0; qg < 2; qg++){
      sacc[qg] = mfma16(ones8, pa[qg][0], sacc[qg]);
      sacc[qg] = mfma16(ones8, pa[qg][1], sacc[qg]);
    }
    #pragma unroll
    for (int dt = 0; dt < 4; dt++){
      int row = 16*dt + cl;
      int sw = swzV(row) << 4;
      const char* rp = Vb + (row << 7);
      bf16x8 vf0 = *(const bf16x8*)(rp + ((16*cg) ^ sw));
      bf16x8 vf1 = *(const bf16x8*)(rp + ((64 + 16*cg) ^ sw));
      #pragma unroll
      for (int qg = 0; qg < 2; qg++){
        o[qg][dt] = mfma16(pa[qg][0], vf0, o[qg][dt]);
        o[qg][dt] = mfma16(pa[qg][1], vf1, o[qg][dt]);
      }
    }
    __builtin_amdgcn_s_setprio(0);

    asm volatile("s_waitcnt vmcnt(0)" ::: "memory");
    __syncthreads();
    wd_cur[0] = wd_nxt[0];
    wd_cur[1] = wd_nxt[1];
  }

  #pragma unroll
  for (int qg = 0; qg < 2; qg++){
    float inv = 1.0f / sacc[qg][0];
    float ir0 = __shfl(inv, (lane & 48) | (cg*4 + 0));
    float ir1 = __shfl(inv, (lane & 48) | (cg*4 + 1));
    float ir2 = __shfl(inv, (lane & 48) | (cg*4 + 2));
    float ir3 = __shfl(inv, (lane & 48) | (cg*4 + 3));
    int qbase = qw + qg*16 + cg*4;
    #pragma unroll
    for (int dt = 0; dt < 4; dt++){
      bf16_t* op = att + ((long)(b * L1_) + qbase) * INNER_ + h * D_ + 16*dt + cl;
      op[0] = (bf16_t)(o[qg][dt][0] * ir0);
      op[INNER_] = (bf16_t)(o[qg][dt][1] * ir1);
      op[2*INNER_] = (bf16_t)(o[qg][dt][2] * ir2);
      op[3*INNER_] = (bf16_t)(o[qg][dt][3] * ir3);
    }
  }
}

// ---------------- output GEMM, XCD-chunked 1D grid ----------------
__global__ __launch_bounds__(256)
void k_out(const bf16_t* __restrict__ A, const bf16_t* __restrict__ Wot,
           const float* __restrict__ bo, float* __restrict__ out)
{
  __shared__ __align__(16) char As[2][128*64*2];
  __shared__ __align__(16) char Bs[2][64*64*2];
  int lin = blockIdx.x;
  int xcd = lin & 7, idx = lin >> 3;
  int tid = threadIdx.x;
  int w = tid >> 6, lane = tid & 63, cl = lane & 15, cg = lane >> 4;
  int wr = w >> 1, wc = w & 1;
  int m0 = (xcd * 16 + (idx & 15)) * 128, n0 = (idx >> 4) * 64;
  const char* Ab = (const char*)A;
  const char* Bb = (const char*)Wot;

  f32x4 acc[4][2];
  #pragma unroll
  for (int i = 0; i < 4; i++)
    #pragma unroll
    for (int j = 0; j < 2; j++) acc[i][j] = (f32x4){0,0,0,0};

  auto stage = [&](int kb, int buf){
    #pragma unroll
    for (int c = 0; c < 4; c++){
      int e = c * 4096 + tid * 16;
      int row = e >> 7, irb = e & 127;
      gl_lds16(Ab + (long)(m0 + row) * 1024 + kb * 128 + (irb ^ ((row & 7) << 4)), As[buf] + e);
    }
    #pragma unroll
    for (int c = 0; c < 2; c++){
      int e = c * 4096 + tid * 16;
      int row = e >> 7, irb = e & 127;
      gl_lds16(Bb + (long)(n0 + row) * 1024 + kb * 128 + (irb ^ ((row & 7) << 4)), Bs[buf] + e);
    }
  };

  stage(0, 0);
  for (int kb = 0; kb < 8; kb++){
    int buf = kb & 1;
    if (kb < 7){
      stage(kb + 1, buf ^ 1);
      asm volatile("s_waitcnt vmcnt(6)" ::: "memory");
    } else {
      asm volatile("s_waitcnt vmcnt(0)" ::: "memory");
    }
    __syncthreads();
    #pragma unroll
    for (int kc = 0; kc < 2; kc++){
      int kk = kc * 32 + cg * 8;
      bf16x8 af[4], bfr[2];
      #pragma unroll
      for (int mt = 0; mt < 4; mt++){
        int row = wr * 64 + mt * 16 + cl;
        af[mt] = *(const bf16x8*)(As[buf] + (row << 7) + ((kk << 1) ^ ((row & 7) << 4)));
      }
      #pragma unroll
      for (int nt = 0; nt < 2; nt++){
        int row = wc * 32 + nt * 16 + cl;
        bfr[nt] = *(const bf16x8*)(Bs[buf] + (row << 7) + ((kk << 1) ^ ((row & 7) << 4)));
      }
      #pragma unroll
      for (int mt = 0; mt < 4; mt++)
        #pragma unroll
        for (int nt = 0; nt < 2; nt++)
          acc[mt][nt] = mfma16(af[mt], bfr[nt], acc[mt][nt]);
    }
    __syncthreads();
  }
  #pragma unroll
  for (int mt = 0; mt < 4; mt++)
    #pragma unroll
    for (int nt = 0; nt < 2; nt++){
      int row = m0 + wr * 64 + mt * 16 + cg * 4;
      int col = n0 + wc * 32 + nt * 16 + cl;
      float bias = bo[col];
      #pragma unroll
      for (int r = 0; r < 4; r++)
        out[(long)(row + r) * C_ + col] = acc[mt][nt][r] + bias;
    }
}

extern "C" void kernel_launch(void* const* d_in, const int* in_sizes, int n_in,
                              void* d_out, int out_size, void* d_ws, size_t ws_size,
                              hipStream_t stream)
{
  const float* x    = (const float*)d_in[0];
  const float* ctx  = (const float*)d_in[1];
  const void*  mask = d_in[2];
  const float* Wq   = (const float*)d_in[3];
  const float* Wk   = (const float*)d_in[4];
  const float* Wv   = (const float*)d_in[5];
  const float* Wo   = (const float*)d_in[6];
  const float* bo   = (const float*)d_in[7];
  const float* regt = (const float*)d_in[8];
  float* out = (float*)d_out;

  char* ws = (char*)d_ws;
  size_t off = 256;
  unsigned int* maskp = (unsigned int*)(ws + off);    off += (size_t)16384 * 66 * 4;
  bf16_t* Qw  = (bf16_t*)(ws + off);                  off += (size_t)B_*H_*L1_*D_*2;
  bf16_t* Kw  = (bf16_t*)(ws + off);                  off += (size_t)B_*H_*LKP_*D_*2;
  bf16_t* Vtw = (bf16_t*)(ws + off);                  off += (size_t)B_*H_*D_*LKP_*2;
  bf16_t* Att = (bf16_t*)(ws + off);                  off += (size_t)B_*L1_*INNER_*2;
  bf16_t* Wqt = (bf16_t*)(ws + off);                  off += (size_t)C_*INNER_*2;
  bf16_t* Wkt = (bf16_t*)(ws + off);                  off += (size_t)C_*INNER_*2;
  bf16_t* Wvt = (bf16_t*)(ws + off);                  off += (size_t)C_*INNER_*2;
  bf16_t* Wot = (bf16_t*)(ws + off);                  off += (size_t)C_*INNER_*2;
  (void)ws_size; (void)in_sizes; (void)n_in; (void)out_size;

  k_prep<<<5120, 256, 0, stream>>>(Wq, Wk, Wv, Wo, Wqt, Wkt, Wvt, Wot, mask, maskp);
  k_proj<<<1600, 256, 0, stream>>>(x, ctx, regt, Wqt, Wkt, Wvt, Qw, Kw, Vtw);
  k_attn<<<512, 512, 0, stream>>>(Qw, Kw, Vtw, maskp, Att);
  k_out<<<640, 256, 0, stream>>>(Att, Wot, bo, out);
}

// Round 14
// 176.506 us; speedup vs baseline: 1.5304x; 1.2650x over previous
//
#include <hip/hip_runtime.h>
#include <hip/hip_bf16.h>

#define B_ 8
#define L1_ 2048
#define L2_ 2048
#define C_ 320
#define H_ 8
#define D_ 64
#define NREG_ 4
#define INNER_ 512
#define LK_ 2052
#define LKP_ 2112   /* 33*64 padded key length */
#define NKV_TILES 33
#define LOG2E 1.44269504f
#define QSCALE (0.125f * LOG2E)   /* folded into Wq at transpose time */

// KV ORDER: [ctx (0..2047) | reg tokens (2048..2051) | pad] — mask byte idx == kv.

typedef __bf16 bf16_t;
typedef __attribute__((ext_vector_type(8))) __bf16 bf16x8;
typedef __attribute__((ext_vector_type(4))) __bf16 bf16x4;
typedef __attribute__((ext_vector_type(4))) float f32x4;
typedef __attribute__((ext_vector_type(4))) unsigned int u32x4;

__device__ __forceinline__ f32x4 mfma16(bf16x8 a, bf16x8 b, f32x4 c){
  return __builtin_amdgcn_mfma_f32_16x16x32_bf16(a, b, c, 0, 0, 0);
}

__device__ __forceinline__ void gl_lds16(const char* g, char* l){
  __builtin_amdgcn_global_load_lds(
      (const __attribute__((address_space(1))) unsigned int*)g,
      (__attribute__((address_space(3))) unsigned int*)l, 16, 0, 0);
}

__device__ __forceinline__ float fexp2(float x){
  float r; asm("v_exp_f32 %0, %1" : "=v"(r) : "v"(x)); return r;
}

__device__ __forceinline__ unsigned cvtpk(float a, float b){
  unsigned r; asm("v_cvt_pk_bf16_f32 %0, %1, %2" : "=v"(r) : "v"(a), "v"(b)); return r;
}

__device__ __forceinline__ unsigned byte2bits(unsigned u){
  unsigned b = 0;
  b |= (u & 0x000000FFu) ? 1u : 0u;
  b |= (u & 0x0000FF00u) ? 2u : 0u;
  b |= (u & 0x00FF0000u) ? 4u : 0u;
  b |= (u & 0xFF000000u) ? 8u : 0u;
  return b;
}

__device__ __forceinline__ unsigned packmask(u32x4 a, u32x4 c){
  unsigned wdv = 0;
  wdv |= byte2bits(a[0]);
  wdv |= byte2bits(a[1]) << 4;
  wdv |= byte2bits(a[2]) << 8;
  wdv |= byte2bits(a[3]) << 12;
  wdv |= byte2bits(c[0]) << 16;
  wdv |= byte2bits(c[1]) << 20;
  wdv |= byte2bits(c[2]) << 24;
  wdv |= byte2bits(c[3]) << 28;
  return wdv;
}

__device__ __forceinline__ int swzK(int row){ return (row & 3) | ((row >> 1) & 4); }
__device__ __forceinline__ int swzV(int row){ return row & 7; }

// ---------------- fused prep (MLP-raised): transpose + cvt + mask pack ----------------
// blocks [0,1024): transpose; [1024,2304): x cvt (4 grp/thr);
// [2304,3624): ctx cvt (4 grp/thr); [3624,5672): mask (2 row-quads/block).
__global__ __launch_bounds__(256)
void k_prep(const float* __restrict__ Wq, const float* __restrict__ Wk,
            const float* __restrict__ Wv, const float* __restrict__ Wo,
            bf16_t* __restrict__ Wqt, bf16_t* __restrict__ Wkt,
            bf16_t* __restrict__ Wvt, bf16_t* __restrict__ Wot,
            const float* __restrict__ x, const float* __restrict__ ctx,
            const float* __restrict__ regt,
            bf16_t* __restrict__ xb, bf16_t* __restrict__ ctxb,
            const void* __restrict__ maskv, unsigned int* __restrict__ maskp)
{
  int bid = blockIdx.x;
  int tid = threadIdx.x;
  if (bid < 1024){
    int z = bid >> 8, r = bid & 255, bx = r & 15, by = r >> 4;
    int K = (z < 3) ? C_ : INNER_;
    int N = (z < 3) ? INNER_ : C_;
    if (bx * 32 >= N || by * 32 >= K) return;
    const float* W = (z == 0) ? Wq : (z == 1) ? Wk : (z == 2) ? Wv : Wo;
    bf16_t* Wt = (z == 0) ? Wqt : (z == 1) ? Wkt : (z == 2) ? Wvt : Wot;
    float sc = (z == 0) ? QSCALE : 1.0f;
    __shared__ float t[32][33];
    int n0 = bx * 32, k0 = by * 32;
    int tx = tid & 31, ty = tid >> 5;
    for (int rr = ty; rr < 32; rr += 8) t[rr][tx] = W[(long)(k0 + rr) * N + n0 + tx];
    __syncthreads();
    for (int rr = ty; rr < 32; rr += 8) Wt[(long)(n0 + rr) * K + k0 + tx] = (bf16_t)(t[tx][rr] * sc);
  } else if (bid < 2304){
    // x cvt: 4 independent f32x4 loads -> 2 bf16x8 stores (16 consecutive floats)
    long g0 = ((long)(bid - 1024) * 256 + tid) * 4;
    f32x4 v0 = *(const f32x4*)(x + g0 * 4);
    f32x4 v1 = *(const f32x4*)(x + g0 * 4 + 4);
    f32x4 v2 = *(const f32x4*)(x + g0 * 4 + 8);
    f32x4 v3 = *(const f32x4*)(x + g0 * 4 + 12);
    union { u32x4 u; bf16x8 v; } pkA, pkB;
    pkA.u = (u32x4){cvtpk(v0[0], v0[1]), cvtpk(v0[2], v0[3]),
                    cvtpk(v1[0], v1[1]), cvtpk(v1[2], v1[3])};
    pkB.u = (u32x4){cvtpk(v2[0], v2[1]), cvtpk(v2[2], v2[3]),
                    cvtpk(v3[0], v3[1]), cvtpk(v3[2], v3[3])};
    *(bf16x8*)(xb + g0 * 4) = pkA.v;
    *(bf16x8*)(xb + g0 * 4 + 8) = pkB.v;
  } else if (bid < 3624){
    // ctx cvt: [ctx | reg | pad]; 4 groups/thread, per-group row/col
    long g0 = ((long)(bid - 2304) * 256 + tid) * 4;
    f32x4 vv[4];
    #pragma unroll
    for (int gg = 0; gg < 4; gg++){
      long g = g0 + gg;
      long row = g / 80;
      int col = (int)(g - row * 80) * 4;
      int b = (int)(row / LKP_);
      int rr = (int)(row - (long)b * LKP_);
      f32x4 v = (f32x4){0,0,0,0};
      if (rr < L2_)      v = *(const f32x4*)(ctx + ((long)(b * L1_ + rr)) * C_ + col);
      else if (rr < LK_) v = *(const f32x4*)(regt + (rr - L2_) * C_ + col);
      vv[gg] = v;
    }
    union { u32x4 u; bf16x8 v; } pkA, pkB;
    pkA.u = (u32x4){cvtpk(vv[0][0], vv[0][1]), cvtpk(vv[0][2], vv[0][3]),
                    cvtpk(vv[1][0], vv[1][1]), cvtpk(vv[1][2], vv[1][3])};
    pkB.u = (u32x4){cvtpk(vv[2][0], vv[2][1]), cvtpk(vv[2][2], vv[2][3]),
                    cvtpk(vv[3][0], vv[3][1]), cvtpk(vv[3][2], vv[3][3])};
    *(bf16x8*)(ctxb + g0 * 4) = pkA.v;
    *(bf16x8*)(ctxb + g0 * 4 + 8) = pkB.v;
  } else {
    // mask pack: 2 row-quads per block (4 independent 16B loads in flight)
    int mq0 = bid - 3624;             // [0,2048)
    int sub = tid >> 6, l = tid & 63;
    int row0 = mq0 * 4 + sub;
    int row1 = (mq0 + 2048) * 4 + sub;
    const unsigned char* mb = (const unsigned char*)maskv;
    const int* mi = (const int*)maskv;
    int bad = 0;
    #pragma unroll
    for (int jj = 0; jj < 4; jj++){
      int j = l + jj * 64;
      if ((j & 3) != 0 && mb[j] != 0) bad = 1;
    }
    int isInt = (__ballot(bad) == 0ull) ? 1 : 0;
    unsigned int* orow0 = maskp + (long)row0 * 66;
    unsigned int* orow1 = maskp + (long)row1 * 66;
    if (!isInt){
      const unsigned char* rp0 = mb + (long)row0 * L2_;
      const unsigned char* rp1 = mb + (long)row1 * L2_;
      u32x4 a0 = *(const u32x4*)(rp0 + 32 * l);
      u32x4 c0 = *(const u32x4*)(rp0 + 32 * l + 16);
      u32x4 a1 = *(const u32x4*)(rp1 + 32 * l);
      u32x4 c1 = *(const u32x4*)(rp1 + 32 * l + 16);
      orow0[l] = packmask(a0, c0);
      orow1[l] = packmask(a1, c1);
      if (l == 0){ orow0[64] = 0x0000000Fu; orow1[64] = 0x0000000Fu; }
      else if (l == 1){ orow0[65] = 0u; orow1[65] = 0u; }
    } else {
      #pragma unroll
      for (int rq = 0; rq < 2; rq++){
        int row = rq ? row1 : row0;
        unsigned int* orow = rq ? orow1 : orow0;
        long base = (long)row * L2_;
        for (int s = 0; s < 33; s++){
          int kv = s * 64 + l;
          int vis;
          if (kv < L2_) vis = (mi[base + kv] != 0);
          else          vis = (kv < LK_);
          unsigned long long bal = __ballot(vis);
          if (l == 0)      orow[2*s]   = (unsigned int)bal;
          else if (l == 1) orow[2*s+1] = (unsigned int)(bal >> 32);
        }
      }
    }
  }
}

// ---------------- fused Q/K/V projection GEMMs, XCD-chunked 1D grid ----------------
__global__ __launch_bounds__(256)
void k_proj(const bf16_t* __restrict__ xb, const bf16_t* __restrict__ ctxb,
            const bf16_t* __restrict__ Wqt, const bf16_t* __restrict__ Wkt,
            const bf16_t* __restrict__ Wvt,
            bf16_t* __restrict__ Qw, bf16_t* __restrict__ Kw, bf16_t* __restrict__ Vtw)
{
  int lin = blockIdx.x;
  int xcd = lin & 7, idx = lin >> 3;
  int mode, mt_, n_;
  if (idx < 64){
    mode = 0;
    mt_ = xcd * 16 + (idx & 15);
    n_ = idx >> 4;
  } else {
    int j = idx - 64;
    mode = 1 + (j & 1);
    int jj = j >> 1;
    n_ = jj & 3;
    int mm = jj >> 2;
    mt_ = mm * 8 + xcd;
    if (mt_ >= 132) return;
  }
  const char* Ab = (const char*)((mode == 0) ? xb : ctxb);
  const char* Wtb = (const char*)((mode == 0) ? Wqt : (mode == 1) ? Wkt : Wvt);
  bf16_t* out = (mode == 0) ? Qw : (mode == 1) ? Kw : Vtw;

  __shared__ __align__(16) char As[2][128*64*2];
  __shared__ __align__(16) char Bs[2][128*64*2];
  int tid = threadIdx.x;
  int w = tid >> 6, lane = tid & 63, cl = lane & 15, cg = lane >> 4;
  int wr = w >> 1, wc = w & 1;
  int m0 = mt_ * 128, n0 = n_ * 128;

  f32x4 acc[4][4];
  #pragma unroll
  for (int i = 0; i < 4; i++)
    #pragma unroll
    for (int j = 0; j < 4; j++) acc[i][j] = (f32x4){0,0,0,0};

  auto stage = [&](int kb, int buf){
    #pragma unroll
    for (int c = 0; c < 4; c++){
      int e = c * 4096 + tid * 16;
      int row = e >> 7, irb = e & 127;
      gl_lds16(Ab + (long)(m0 + row) * 640 + kb * 128 + (irb ^ ((row & 7) << 4)), As[buf] + e);
    }
    #pragma unroll
    for (int c = 0; c < 4; c++){
      int e = c * 4096 + tid * 16;
      int row = e >> 7, irb = e & 127;
      gl_lds16(Wtb + (long)(n0 + row) * 640 + kb * 128 + (irb ^ ((row & 7) << 4)), Bs[buf] + e);
    }
  };

  stage(0, 0);
  for (int kb = 0; kb < 5; ++kb){
    int buf = kb & 1;
    if (kb < 4){
      stage(kb + 1, buf ^ 1);
      asm volatile("s_waitcnt vmcnt(8)" ::: "memory");
    } else {
      asm volatile("s_waitcnt vmcnt(0)" ::: "memory");
    }
    __syncthreads();
    #pragma unroll
    for (int kc = 0; kc < 2; kc++){
      int kk = kc * 32 + cg * 8;
      bf16x8 af[4], bfr[4];
      #pragma unroll
      for (int mt = 0; mt < 4; mt++){
        int row = wr * 64 + mt * 16 + cl;
        af[mt] = *(const bf16x8*)(As[buf] + (row << 7) + ((kk << 1) ^ ((row & 7) << 4)));
      }
      #pragma unroll
      for (int nt = 0; nt < 4; nt++){
        int row = wc * 64 + nt * 16 + cl;
        bfr[nt] = *(const bf16x8*)(Bs[buf] + (row << 7) + ((kk << 1) ^ ((row & 7) << 4)));
      }
      #pragma unroll
      for (int mt = 0; mt < 4; mt++)
        #pragma unroll
        for (int nt = 0; nt < 4; nt++)
          acc[mt][nt] = mfma16(af[mt], bfr[nt], acc[mt][nt]);
    }
    __syncthreads();
  }

  #pragma unroll
  for (int mt = 0; mt < 4; mt++){
    #pragma unroll
    for (int nt = 0; nt < 4; nt++){
      f32x4 v = acc[mt][nt];
      int row = m0 + wr * 64 + mt * 16 + cg * 4;
      int col = n0 + wc * 64 + nt * 16 + cl;
      int h = col >> 6, d = col & 63;
      if (mode == 0){
        int b = row >> 11, l1 = row & 2047;
        bf16_t* p = out + ((long)((b * H_ + h) * L1_ + l1)) * D_ + d;
        #pragma unroll
        for (int r = 0; r < 4; r++) p[r * D_] = (bf16_t)v[r];
      } else if (mode == 1){
        int b = row / LKP_, rr = row - b * LKP_;
        bf16_t* p = out + ((long)((b * H_ + h) * LKP_ + rr)) * D_ + d;
        #pragma unroll
        for (int r = 0; r < 4; r++) p[r * D_] = (bf16_t)v[r];
      } else {
        int b = row / LKP_, rr = row - b * LKP_;
        bf16x4 cv;
        cv[0]=(bf16_t)v[0]; cv[1]=(bf16_t)v[1]; cv[2]=(bf16_t)v[2]; cv[3]=(bf16_t)v[3];
        *(bf16x4*)(out + ((long)((b * H_ + h) * D_ + d)) * LKP_ + rr) = cv;
      }
    }
  }
}

// ---------------- flash attention (frozen from R9) ----------------
__global__ __launch_bounds__(512)
void k_attn(const bf16_t* __restrict__ Q, const bf16_t* __restrict__ K,
            const bf16_t* __restrict__ Vt, const unsigned int* __restrict__ maskp,
            bf16_t* __restrict__ att)
{
  __shared__ __align__(16) char smem[33024]; // K:2x8KB @0, V:2x8KB @16384, LUT @32768
  int lin = blockIdx.x;
  int xcd = lin & 7, idx = lin >> 3;
  int bh = xcd * 8 + (idx >> 3);
  int qb = idx & 7;
  const int b = bh >> 3, h = bh & 7;
  const int tid = threadIdx.x, w = tid >> 6, lane = tid & 63;
  const int cl = lane & 15, cg = lane >> 4;
  const int qw = qb * 256 + w * 32;

  char* lutb = smem + 32768;
  if (tid < 16){
    unsigned n = tid;
    uint2 mk;
    mk.x = ((n & 1u) ? 0x0000FFFFu : 0u) | ((n & 2u) ? 0xFFFF0000u : 0u);
    mk.y = ((n & 4u) ? 0x0000FFFFu : 0u) | ((n & 8u) ? 0xFFFF0000u : 0u);
    *(uint2*)(lutb + tid * 8) = mk;
  }

  const char* Kg = (const char*)(K + (long)bh * LKP_ * D_);
  const char* Vg = (const char*)(Vt + (long)bh * D_ * LKP_);

  bf16x8 qf[2][2];
  const unsigned int* mrow[2];
  #pragma unroll
  for (int qg = 0; qg < 2; qg++){
    const bf16_t* Qb = Q + ((long)bh * L1_ + qw + qg*16 + cl) * D_;
    qf[qg][0] = *(const bf16x8*)(Qb + cg*8);
    qf[qg][1] = *(const bf16x8*)(Qb + 32 + cg*8);
    mrow[qg] = maskp + (long)(b * L1_ + qw + qg*16 + cl) * 66;
  }

  bf16x8 ones8;
  #pragma unroll
  for (int i = 0; i < 8; i++) ones8[i] = (bf16_t)1.0f;

  f32x4 o[2][4];
  f32x4 sacc[2];
  #pragma unroll
  for (int qg = 0; qg < 2; qg++){
    sacc[qg] = (f32x4){0,0,0,0};
    #pragma unroll
    for (int dt = 0; dt < 4; dt++) o[qg][dt] = (f32x4){0,0,0,0};
  }

  const int sp = tid * 16;
  const int srow = sp >> 7, sir = sp & 127;
  const int kgo = (srow << 7) + (sir ^ (swzK(srow) << 4));
  const long vgo = (long)srow * (LKP_ * 2) + (sir ^ (swzV(srow) << 4));

  gl_lds16(Kg + kgo, smem + sp);
  gl_lds16(Vg + vgo, smem + 16384 + sp);
  uint2 wd_cur[2];
  #pragma unroll
  for (int qg = 0; qg < 2; qg++) wd_cur[qg] = *(const uint2*)(mrow[qg]);
  asm volatile("s_waitcnt vmcnt(0)" ::: "memory");
  __syncthreads();

  for (int t = 0; t < NKV_TILES; ++t){
    int tn = (t + 1 < NKV_TILES) ? t + 1 : NKV_TILES - 1;
    gl_lds16(Kg + (long)tn * 8192 + kgo, smem + ((t + 1) & 1) * 8192 + sp);
    gl_lds16(Vg + vgo + tn * 128, smem + 16384 + ((t + 1) & 1) * 8192 + sp);
    uint2 wd_nxt[2];
    #pragma unroll
    for (int qg = 0; qg < 2; qg++) wd_nxt[qg] = *(const uint2*)(mrow[qg] + 2*tn);

    const char* Kb = smem + (t & 1) * 8192;
    const char* Vb = smem + 16384 + (t & 1) * 8192;

    f32x4 s[2][4];
    __builtin_amdgcn_s_setprio(1);
    #pragma unroll
    for (int T = 0; T < 4; T++){
      int row = 32*(T>>1) + 8*(cl>>2) + 4*(T&1) + (cl&3);
      int sw = swzK(row) << 4;
      const char* rp = Kb + (row << 7);
      bf16x8 kf0 = *(const bf16x8*)(rp + ((16*cg) ^ sw));
      bf16x8 kf1 = *(const bf16x8*)(rp + ((64 + 16*cg) ^ sw));
      #pragma unroll
      for (int qg = 0; qg < 2; qg++){
        f32x4 z = (f32x4){0,0,0,0};
        z = mfma16(kf0, qf[qg][0], z);
        z = mfma16(kf1, qf[qg][1], z);
        s[qg][T] = z;
      }
    }
    __builtin_amdgcn_s_setprio(0);

    bf16x8 pa[2][2];
    #pragma unroll
    for (int qg = 0; qg < 2; qg++){
      unsigned wrd[2][4];
      #pragma unroll
      for (int T = 0; T < 4; T++){
        unsigned wsel = (T < 2) ? wd_cur[qg].x : wd_cur[qg].y;
        unsigned nib = (wsel >> (8*cg + 4*(T&1))) & 0xFu;
        uint2 mk = *(const uint2*)(lutb + (nib << 3));
        float p0 = fexp2(s[qg][T][0]);
        float p1 = fexp2(s[qg][T][1]);
        float p2 = fexp2(s[qg][T][2]);
        float p3 = fexp2(s[qg][T][3]);
        unsigned lo = cvtpk(p0, p1) & mk.x;
        unsigned hi = cvtpk(p2, p3) & mk.y;
        wrd[T >> 1][2*(T & 1) + 0] = lo;
        wrd[T >> 1][2*(T & 1) + 1] = hi;
      }
      union { u32x4 u; bf16x8 v; } pk0, pk1;
      pk0.u = (u32x4){wrd[0][0], wrd[0][1], wrd[0][2], wrd[0][3]};
      pk1.u = (u32x4){wrd[1][0], wrd[1][1], wrd[1][2], wrd[1][3]};
      pa[qg][0] = pk0.v;
      pa[qg][1] = pk1.v;
    }

    __builtin_amdgcn_s_setprio(1);
    #pragma unroll
    for (int qg = 0; qg < 2; qg++){
      sacc[qg] = mfma16(ones8, pa[qg][0], sacc[qg]);
      sacc[qg] = mfma16(ones8, pa[qg][1], sacc[qg]);
    }
    #pragma unroll
    for (int dt = 0; dt < 4; dt++){
      int row = 16*dt + cl;
      int sw = swzV(row) << 4;
      const char* rp = Vb + (row << 7);
      bf16x8 vf0 = *(const bf16x8*)(rp + ((16*cg) ^ sw));
      bf16x8 vf1 = *(const bf16x8*)(rp + ((64 + 16*cg) ^ sw));
      #pragma unroll
      for (int qg = 0; qg < 2; qg++){
        o[qg][dt] = mfma16(pa[qg][0], vf0, o[qg][dt]);
        o[qg][dt] = mfma16(pa[qg][1], vf1, o[qg][dt]);
      }
    }
    __builtin_amdgcn_s_setprio(0);

    asm volatile("s_waitcnt vmcnt(0)" ::: "memory");
    __syncthreads();
    wd_cur[0] = wd_nxt[0];
    wd_cur[1] = wd_nxt[1];
  }

  #pragma unroll
  for (int qg = 0; qg < 2; qg++){
    float inv = 1.0f / sacc[qg][0];
    float ir0 = __shfl(inv, (lane & 48) | (cg*4 + 0));
    float ir1 = __shfl(inv, (lane & 48) | (cg*4 + 1));
    float ir2 = __shfl(inv, (lane & 48) | (cg*4 + 2));
    float ir3 = __shfl(inv, (lane & 48) | (cg*4 + 3));
    int qbase = qw + qg*16 + cg*4;
    #pragma unroll
    for (int dt = 0; dt < 4; dt++){
      bf16_t* op = att + ((long)(b * L1_) + qbase) * INNER_ + h * D_ + 16*dt + cl;
      op[0] = (bf16_t)(o[qg][dt][0] * ir0);
      op[INNER_] = (bf16_t)(o[qg][dt][1] * ir1);
      op[2*INNER_] = (bf16_t)(o[qg][dt][2] * ir2);
      op[3*INNER_] = (bf16_t)(o[qg][dt][3] * ir3);
    }
  }
}

// ---------------- output GEMM, XCD-chunked 1D grid ----------------
__global__ __launch_bounds__(256)
void k_out(const bf16_t* __restrict__ A, const bf16_t* __restrict__ Wot,
           const float* __restrict__ bo, float* __restrict__ out)
{
  __shared__ __align__(16) char As[2][128*64*2];
  __shared__ __align__(16) char Bs[2][64*64*2];
  int lin = blockIdx.x;
  int xcd = lin & 7, idx = lin >> 3;
  int tid = threadIdx.x;
  int w = tid >> 6, lane = tid & 63, cl = lane & 15, cg = lane >> 4;
  int wr = w >> 1, wc = w & 1;
  int m0 = (xcd * 16 + (idx & 15)) * 128, n0 = (idx >> 4) * 64;
  const char* Ab = (const char*)A;
  const char* Bb = (const char*)Wot;

  f32x4 acc[4][2];
  #pragma unroll
  for (int i = 0; i < 4; i++)
    #pragma unroll
    for (int j = 0; j < 2; j++) acc[i][j] = (f32x4){0,0,0,0};

  auto stage = [&](int kb, int buf){
    #pragma unroll
    for (int c = 0; c < 4; c++){
      int e = c * 4096 + tid * 16;
      int row = e >> 7, irb = e & 127;
      gl_lds16(Ab + (long)(m0 + row) * 1024 + kb * 128 + (irb ^ ((row & 7) << 4)), As[buf] + e);
    }
    #pragma unroll
    for (int c = 0; c < 2; c++){
      int e = c * 4096 + tid * 16;
      int row = e >> 7, irb = e & 127;
      gl_lds16(Bb + (long)(n0 + row) * 1024 + kb * 128 + (irb ^ ((row & 7) << 4)), Bs[buf] + e);
    }
  };

  stage(0, 0);
  for (int kb = 0; kb < 8; kb++){
    int buf = kb & 1;
    if (kb < 7){
      stage(kb + 1, buf ^ 1);
      asm volatile("s_waitcnt vmcnt(6)" ::: "memory");
    } else {
      asm volatile("s_waitcnt vmcnt(0)" ::: "memory");
    }
    __syncthreads();
    #pragma unroll
    for (int kc = 0; kc < 2; kc++){
      int kk = kc * 32 + cg * 8;
      bf16x8 af[4], bfr[2];
      #pragma unroll
      for (int mt = 0; mt < 4; mt++){
        int row = wr * 64 + mt * 16 + cl;
        af[mt] = *(const bf16x8*)(As[buf] + (row << 7) + ((kk << 1) ^ ((row & 7) << 4)));
      }
      #pragma unroll
      for (int nt = 0; nt < 2; nt++){
        int row = wc * 32 + nt * 16 + cl;
        bfr[nt] = *(const bf16x8*)(Bs[buf] + (row << 7) + ((kk << 1) ^ ((row & 7) << 4)));
      }
      #pragma unroll
      for (int mt = 0; mt < 4; mt++)
        #pragma unroll
        for (int nt = 0; nt < 2; nt++)
          acc[mt][nt] = mfma16(af[mt], bfr[nt], acc[mt][nt]);
    }
    __syncthreads();
  }
  #pragma unroll
  for (int mt = 0; mt < 4; mt++)
    #pragma unroll
    for (int nt = 0; nt < 2; nt++){
      int row = m0 + wr * 64 + mt * 16 + cg * 4;
      int col = n0 + wc * 32 + nt * 16 + cl;
      float bias = bo[col];
      #pragma unroll
      for (int r = 0; r < 4; r++)
        out[(long)(row + r) * C_ + col] = acc[mt][nt][r] + bias;
    }
}

extern "C" void kernel_launch(void* const* d_in, const int* in_sizes, int n_in,
                              void* d_out, int out_size, void* d_ws, size_t ws_size,
                              hipStream_t stream)
{
  const float* x    = (const float*)d_in[0];
  const float* ctx  = (const float*)d_in[1];
  const void*  mask = d_in[2];
  const float* Wq   = (const float*)d_in[3];
  const float* Wk   = (const float*)d_in[4];
  const float* Wv   = (const float*)d_in[5];
  const float* Wo   = (const float*)d_in[6];
  const float* bo   = (const float*)d_in[7];
  const float* regt = (const float*)d_in[8];
  float* out = (float*)d_out;

  char* ws = (char*)d_ws;
  size_t off = 256;
  unsigned int* maskp = (unsigned int*)(ws + off);    off += (size_t)16384 * 66 * 4;
  bf16_t* Qw  = (bf16_t*)(ws + off);                  off += (size_t)B_*H_*L1_*D_*2;
  bf16_t* Kw  = (bf16_t*)(ws + off);                  off += (size_t)B_*H_*LKP_*D_*2;
  bf16_t* Vtw = (bf16_t*)(ws + off);                  off += (size_t)B_*H_*D_*LKP_*2;
  size_t Roff = off;
  bf16_t* xb   = (bf16_t*)(ws + Roff);
  bf16_t* ctxb = (bf16_t*)(ws + Roff + (size_t)16384*C_*2);
  bf16_t* Att  = (bf16_t*)(ws + Roff);
  off = Roff + (size_t)16384*C_*2 + (size_t)16896*C_*2;
  bf16_t* Wqt = (bf16_t*)(ws + off);                  off += (size_t)C_*INNER_*2;
  bf16_t* Wkt = (bf16_t*)(ws + off);                  off += (size_t)C_*INNER_*2;
  bf16_t* Wvt = (bf16_t*)(ws + off);                  off += (size_t)C_*INNER_*2;
  bf16_t* Wot = (bf16_t*)(ws + off);                  off += (size_t)C_*INNER_*2;
  (void)ws_size; (void)in_sizes; (void)n_in; (void)out_size;

  k_prep<<<5672, 256, 0, stream>>>(Wq, Wk, Wv, Wo, Wqt, Wkt, Wvt, Wot,
                                   x, ctx, regt, xb, ctxb, mask, maskp);
  k_proj<<<1600, 256, 0, stream>>>(xb, ctxb, Wqt, Wkt, Wvt, Qw, Kw, Vtw);
  k_attn<<<512, 512, 0, stream>>>(Qw, Kw, Vtw, maskp, Att);
  k_out<<<640, 256, 0, stream>>>(Att, Wot, bo, out);
}